// Round 12
// baseline (18912.331 us; speedup 1.0000x reference)
//
#include <hip/hip_runtime.h>
#include <hip/hip_cooperative_groups.h>

namespace cg = cooperative_groups;

#define NBLK 256
#define NTHR 512

// workspace layout (float offsets)
constexpr int WS_H    = 0;            // 128*1024   h state (MALL-coherent via sc stores)
constexpr int WS_HHS  = 131072;       // 128*256    hh state
constexpr int WS_Y    = 163840;       // 128*128    y = proj output
constexpr int WS_WEFF = 180224;       // 256*12288  folded hyper weights (plain, L2-cached)
constexpr int WS_BAR  = WS_WEFF + 256*12288;   // barrier counters (uint), <=1024 uints (proven safe)
// layout (uint idx): root @0 ; leaf[g] @ 32+g*32 (g=0..15) ; go[g] @ 544+g*32

__device__ __forceinline__ float dot4(float4 a, float4 b){
  return a.x*b.x + a.y*b.y + a.z*b.z + a.w*b.w;
}
__device__ __forceinline__ float sigf(float x){ return 1.0f/(1.0f + expf(-x)); }
__device__ __forceinline__ float gumb(float u){
  u = fminf(fmaxf(u, 1e-7f), 1.0f - 1e-7f);
  return -logf(-logf(u));
}

// coherent write-through store (reaches MALL; vmcnt-tracked)
__device__ __forceinline__ void st_cg(float* p, float v){
  asm volatile("global_store_dword %0, %1, off sc0 sc1" :: "v"(p), "v"(v) : "memory");
}

// grid barrier (16 groups x 16 blocks, broadcast release) — r7-proven
__device__ __forceinline__ void gridbar(unsigned* barc, unsigned n){
  asm volatile("s_waitcnt vmcnt(0)" ::: "memory");
  __syncthreads();
  if (threadIdx.x == 0){
    const unsigned g = blockIdx.x >> 4;
    unsigned old = __hip_atomic_fetch_add(barc + 32 + g*32, 1u,
                     __ATOMIC_RELAXED, __HIP_MEMORY_SCOPE_AGENT);
    if (old + 1 == n*16)
      __hip_atomic_fetch_add(barc, 1u, __ATOMIC_RELAXED, __HIP_MEMORY_SCOPE_AGENT);
    if ((blockIdx.x & 15) == 0){
      while (__hip_atomic_load(barc, __ATOMIC_RELAXED, __HIP_MEMORY_SCOPE_AGENT) < n*16)
        __builtin_amdgcn_s_sleep(1);
      __hip_atomic_store(barc + 544 + g*32, n, __ATOMIC_RELAXED, __HIP_MEMORY_SCOPE_AGENT);
    } else {
      while (__hip_atomic_load(barc + 544 + g*32, __ATOMIC_RELAXED, __HIP_MEMORY_SCOPE_AGENT) < n)
        __builtin_amdgcn_s_sleep(1);
    }
  }
  __syncthreads();
  __builtin_amdgcn_fence(__ATOMIC_ACQUIRE, "agent");
}

// Register windows (<=128 live):
//  P1: wWh 64 (reloaded per step, dead outside) + stage regs 12 + tile operands 20
//  P3: wf 48 + pf 16 + v 12 (no wWh)
// P1 h/hh reads: LDS ring staging — each batch fetched from MALL ONCE per block
// (was 4-way L1-shared stream in r7), latency hidden under consume compute.
extern "C" __global__ void __launch_bounds__(NTHR, 1)
vae_kernel(const float* __restrict__ z,     const float* __restrict__ cls,
           const float* __restrict__ fcW,   const float* __restrict__ fcb,
           const float* __restrict__ Wx,    const float* __restrict__ Wh,
           const float* __restrict__ bias0, const float* __restrict__ hWx,
           const float* __restrict__ hWh,   const float* __restrict__ hb,
           const float* __restrict__ Whz_x, const float* __restrict__ Whz_h,
           const float* __restrict__ Whz_b, const float* __restrict__ Wdz_x,
           const float* __restrict__ Wdz_h, const float* __restrict__ Wdz_b,
           const float* __restrict__ projW, const float* __restrict__ projb,
           const float* __restrict__ eps_,  const float* __restrict__ umix,
           const float* __restrict__ upen,
           float* __restrict__ out, float* __restrict__ ws)
{
  cg::grid_group grid = cg::this_grid();
  const int tid = threadIdx.x;
  const int bid = blockIdx.x;
  const int l = tid & 63;          // lane
  const int w = tid >> 6;          // wave 0..7
  const int rq = w & 3;            // gate index (P1/P3)
  const int bh = w >> 2;           // batch-half (P1/P3)

  float* hws   = ws + WS_H;
  float* hhws  = ws + WS_HHS;
  float* yws   = ws + WS_Y;
  float* weffw = ws + WS_WEFF;
  unsigned* barc = (unsigned*)(ws + WS_BAR);

  // LDS (~119 KB)
  __shared__ __align__(16) float lds_h[16896];   // P1 stage ring 2x5120 / P2 y 128x132 / P3 scr 128x50
  __shared__ __align__(16) float lds_GH[2176];   // GH[b][17]
  __shared__ __align__(16) float lds_Gp[640];    // Gp[b][5]
  __shared__ __align__(16) float lds_prev[1152]; // prev[b][9]
  __shared__ __align__(16) float lds_hWxs[4096]; // hWx h-cols per gate
  __shared__ __align__(16) float lds_hWhs[1024]; // hWh per gate
  __shared__ __align__(16) float lds_pj[1024];   // proj row
  __shared__ __align__(16) float lds_cgx[2048];  // cgxr[tid][4]
  __shared__ __align__(16) float lds_cg4[512];   // cg4r[b][4] (b<128)
  __shared__ float lds_wxp[80];
  __shared__ float lds_hwxp[20];
  __shared__ float lds_b0[16];

  //==================== INIT ====================
  if (bid == 0 && tid < 33){
    unsigned* pc = (tid == 0) ? barc
                 : (tid < 17) ? (barc + 32 + (tid-1)*32)
                              : (barc + 544 + (tid-17)*32);
    __hip_atomic_store(pc, 0u, __ATOMIC_RELAXED, __HIP_MEMORY_SCOPE_AGENT);
  }

  const bool isproj = (bid >= 128 && bid < 251);
  const int prow = bid - 128;
  float pjb = 0.f;
  if (isproj) pjb = projb[prow];

  // --- LDS weight staging: hWx h-cols per gate, hWh per gate, proj row ---
  for (int i = tid; i < 4096; i += NTHR){
    int gi = i >> 10, c = i & 1023;
    lds_hWxs[i] = hWx[(size_t)(gi*256 + bid)*1167 + 143 + c];
  }
  for (int i = tid; i < 1024; i += NTHR){
    int gi = i >> 8, c = i & 255;
    lds_hWhs[i] = hWh[(((size_t)(gi*256 + bid)) << 8) + c];
  }
  if (isproj)
    for (int i = tid; i < 1024; i += NTHR)
      lds_pj[i] = projW[((size_t)prow << 10) + i];

  // --- per-thread elementwise state (b = tid>>2, j = tid&3); cgxr/cg4r -> LDS ---
  const int eb = tid >> 2, ej = tid & 3;
  #pragma unroll
  for (int k = 0; k < 4; ++k){
    const float* wr = Wx + (size_t)(k*1024 + bid*4 + ej)*143;
    float a = 0.f;
    for (int n = 0; n < 10; ++n) a += cls[eb*10+n]*wr[5+n];
    const float* zr = z + (eb << 7);
    #pragma unroll 8
    for (int i = 0; i < 128; ++i) a += zr[i]*wr[15+i];
    lds_cgx[tid*4+k] = a;
  }
  float cst;
  {
    int col = 1024 + bid*4 + ej;
    float a = fcb[col];
    const float* wr = fcW + (col << 7);
    const float* zr = z + (eb << 7);
    #pragma unroll 8
    for (int i = 0; i < 128; ++i) a += zr[i]*wr[i];
    cst = tanhf(a);
  }
  {
    int col = bid*4 + ej;
    float a = fcb[col];
    const float* wr = fcW + (col << 7);
    const float* zr = z + (eb << 7);
    #pragma unroll 8
    for (int i = 0; i < 128; ++i) a += zr[i]*wr[i];
    st_cg(&hws[(eb << 10) + col], tanhf(a));
  }
  float chst = 0.f;
  if (tid < 128){
    int b = tid;
    const float* zr = z + (b << 7);
    #pragma unroll
    for (int gi = 0; gi < 4; ++gi){
      int row = gi*256 + bid;
      const float* wr = hWx + (size_t)row*1167;
      float a = hb[row];
      for (int n = 0; n < 10; ++n) a += cls[b*10+n]*wr[5+n];
      #pragma unroll 8
      for (int i = 0; i < 128; ++i) a += zr[i]*wr[15+i];
      lds_cg4[b*4+gi] = a;
    }
    {
      int col = 2304 + bid;
      float a = fcb[col];
      const float* wr = fcW + (col << 7);
      #pragma unroll 8
      for (int i = 0; i < 128; ++i) a += zr[i]*wr[i];
      chst = tanhf(a);
    }
    {
      int col = 2048 + bid;
      float a = fcb[col];
      const float* wr = fcW + (col << 7);
      #pragma unroll 8
      for (int i = 0; i < 128; ++i) a += zr[i]*wr[i];
      st_cg(&hhws[(b << 8) + bid], tanhf(a));
    }
    lds_prev[tid*9+0] = 0.f; lds_prev[tid*9+1] = 0.f; lds_prev[tid*9+2] = 1.f;
    lds_prev[tid*9+3] = 0.f; lds_prev[tid*9+4] = 0.f;
  }
  if (tid < 80){
    int r16 = tid/5, p = tid - r16*5;
    lds_wxp[tid] = Wx[(size_t)((r16>>2)*1024 + bid*4 + (r16&3))*143 + p];
  }
  if (tid < 20){
    int gi = tid/5, p = tid - gi*5;
    lds_hwxp[tid] = hWx[(size_t)(gi*256 + bid)*1167 + p];
  }
  if (tid < 16) lds_b0[tid] = bias0[(tid>>2)*1024 + bid*4 + (tid&3)];

  // --- Weff fold: Weff_m[r=k*4+j][c] = sum_z Wdz_m[k*1024+bid*4+j][z] * Whz_m[k*64+z][c] ---
  {
    const float* Wdzp[3] = {Wdz_x, Wdz_h, Wdz_b};
    const float* Whzp[3] = {Whz_x, Whz_h, Whz_b};
    for (int n = 0; n < 24; ++n){
      int gidx = tid + 512*n;
      int m = gidx >> 12, rem = gidx & 4095;
      int r = rem >> 8, c = rem & 255;
      int k = r >> 2, j = r & 3;
      const float* wd = Wdzp[m] + (size_t)(k*1024 + bid*4 + j)*64;
      const float* wzb = Whzp[m] + c;
      float a = 0.f;
      #pragma unroll 8
      for (int zz = 0; zz < 64; ++zz) a += wd[zz]*wzb[(k*64+zz) << 8];
      weffw[(size_t)bid*12288 + gidx] = a;
    }
  }
  grid.sync();   // publishes init state + zeroed counters

  unsigned barno = 0;

  const float4* wx4  = (const float4*)lds_hWxs + (rq << 8);
  const float4* whh4 = (const float4*)lds_hWhs + (rq << 6);
  const float4* pj4  = (const float4*)lds_pj;

  //==================== time loop ====================
  for (int t = 0; t <= 128; ++t){
    //---------------- P1: LDS-ring staged h/hh; wave (rq,bh) consumes its half ----------------
    {
      // gate-rq Wh rows reloaded per step (dead during P2/P3)
      float4 wWh[4][4];
      #pragma unroll
      for (int j = 0; j < 4; ++j){
        const int row = rq*1024 + bid*4 + j;
        #pragma unroll
        for (int m = 0; m < 4; ++m)
          wWh[j][m] = *((const float4*)(Wh + ((size_t)row << 10) + m*256) + l);
      }

      auto p1c = [&](float4 a0, float4 a1, float4 a2, float4 a3, float4 hv, int b){
        float acc[4];
        #pragma unroll
        for (int j = 0; j < 4; ++j)
          acc[j] = dot4(a0,wWh[j][0]) + dot4(a1,wWh[j][1])
                 + dot4(a2,wWh[j][2]) + dot4(a3,wWh[j][3]);
        float gac = dot4(a0, wx4[l]) + dot4(a1, wx4[64+l]) + dot4(a2, wx4[128+l])
                  + dot4(a3, wx4[192+l]) + dot4(hv, whh4[l]);
        const bool b5 = (l & 32), b4_ = (l & 16), b3 = (l & 8);
        // stage 32: acc pairs split; gac butterflies along
        #pragma unroll
        for (int q = 0; q < 2; ++q){
          float snd = b5 ? acc[q] : acc[q+2];
          float rcv = __shfl_xor(snd, 32, 64);
          acc[q] = (b5 ? acc[q+2] : acc[q]) + rcv;
        }
        gac += __shfl_xor(gac, 32, 64);
        // stage 16
        {
          float snd = b4_ ? acc[0] : acc[1];
          float rcv = __shfl_xor(snd, 16, 64);
          acc[0] = (b4_ ? acc[1] : acc[0]) + rcv;
        }
        gac += __shfl_xor(gac, 16, 64);
        // stage 8: split acc vs gac, shared butterfly
        {
          float snd = b3 ? acc[0] : gac;
          float rcv = __shfl_xor(snd, 8, 64);
          float s = (b3 ? gac : acc[0]) + rcv;
          s += __shfl_xor(s, 4, 64);
          s += __shfl_xor(s, 2, 64);
          s += __shfl_xor(s, 1, 64);
          if ((l & 15) == 0)
            lds_GH[b*17 + rq*4 + (b5 ? 2 : 0) + (b4_ ? 1 : 0)] = s;
          else if (l == 8)
            lds_Gp[b*5 + rq] = s;
        }
        // proj row, balanced across gates via (b&3)==rq
        if (isproj && ((b & 3) == rq)){
          float ya = dot4(a0,pj4[l]) + dot4(a1,pj4[64+l]) + dot4(a2,pj4[128+l])
                   + dot4(a3,pj4[192+l]);
          ya += __shfl_xor(ya, 32, 64);
          ya += __shfl_xor(ya, 16, 64);
          ya += __shfl_xor(ya, 8, 64);
          ya += __shfl_xor(ya, 4, 64);
          ya += __shfl_xor(ya, 2, 64);
          ya += __shfl_xor(ya, 1, 64);
          if (l == 0) st_cg(&yws[(b << 7) + prow], ya + pjb);
        }
      };

      // ring tile i (0..31): batches {2i,2i+1} (half A) + {64+2i,64+2i+1} (half B)
      // slot layout (floats): batch-slot q (0..3): h chunk m at q*1280 + m*256,
      // hh at q*1280 + 1024. 24 chunks/tile (16 h + 4 hh + 4 dup-hh), wave w
      // stages chunks {w, w+8, w+16}: c<16 -> (q=c>>2, m=c&3), else hh q=(c-16)&3.
      float4 rr[3];
      int doff[3];
      auto issue = [&](int i){
        #pragma unroll
        for (int k = 0; k < 3; ++k){
          const int c = w + 8*k;
          const int q = (c < 16) ? (c >> 2) : ((c - 16) & 3);
          const int b = (q < 2) ? (2*i + q) : (62 + 2*i + q);
          const float* src = (c < 16)
            ? hws + ((size_t)b << 10) + ((size_t)(c & 3) << 8)
            : hhws + ((size_t)b << 8);
          rr[k] = ((const float4*)src)[l];
          doff[k] = q*1280 + ((c < 16) ? ((c & 3) << 8) : 1024);
        }
      };
      auto writeslot = [&](float* slot){
        #pragma unroll
        for (int k = 0; k < 3; ++k)
          ((float4*)(slot + doff[k]))[l] = rr[k];
      };

      float* slotA = lds_h;
      float* slotB = lds_h + 5120;
      issue(0);
      writeslot(slotA);
      for (int i = 0; i < 32; ++i){
        float* cur = (i & 1) ? slotB : slotA;
        float* nxt = (i & 1) ? slotA : slotB;
        __syncthreads();                 // cur complete (all waves' writes visible)
        if (i < 31) issue(i+1);          // loads fly under consume
        #pragma unroll
        for (int u = 0; u < 2; ++u){
          const int q = bh*2 + u;
          const int b = bh ? (64 + 2*i + u) : (2*i + u);
          const float4* hp = (const float4*)(cur + q*1280);
          const float4 a0 = hp[l], a1 = hp[64+l], a2 = hp[128+l], a3 = hp[192+l];
          const float4 hv = ((const float4*)(cur + q*1280 + 1024))[l];
          p1c(a0,a1,a2,a3,hv, b);
        }
        if (i < 31) writeslot(nxt);      // compiler inserts vmcnt wait on rr
      }
    }
    gridbar(barc, ++barno);

    // prefetch P3 folded weights — latency hides under P2
    float4 wf[12];
    #pragma unroll
    for (int m = 0; m < 3; ++m)
      #pragma unroll
      for (int j = 0; j < 4; ++j)
        wf[m*4+j] = *((const float4*)(weffw + (size_t)bid*12288 + m*4096 + ((rq*4+j) << 8)) + l);

    //---------------- P2: sampling (t-1, redundant per block), 4 lanes/batch ----------------
    if (t >= 1){
      // y copy global->LDS padded stride 132 (all 512 threads)
      {
        const float4* ysrc = (const float4*)yws;
        float4 q4[8];
        #pragma unroll
        for (int k = 0; k < 8; ++k) q4[k] = ysrc[(tid>>2)*32 + (tid&3)*8 + k];
        float4* dst = (float4*)(lds_h + (tid>>2)*132 + (tid&3)*32);
        #pragma unroll
        for (int k = 0; k < 8; ++k) dst[k] = q4[k];
      }
      const int sb = tid >> 2, sq = tid & 3;   // batch, quarter
      float gm[5];
      #pragma unroll
      for (int i = 0; i < 5; ++i) gm[i] = gumb(umix[((t-1)*128 + sb)*20 + sq*5 + i]);
      const float gpe = (sq < 3) ? gumb(upen[((t-1)*128 + sb)*3 + sq]) : -1e30f;
      const float e0 = eps_[((t-1)*128 + sb)*2 + 0];
      const float e1 = eps_[((t-1)*128 + sb)*2 + 1];
      __syncthreads();
      const float* yb = lds_h + sb*132;
      float best = -1e30f; int km = 0;
      #pragma unroll
      for (int i = 0; i < 5; ++i){
        float v = yb[sq*5+i] + gm[i];
        if (v > best){ best = v; km = sq*5+i; }
      }
      #pragma unroll
      for (int d = 1; d <= 2; d <<= 1){
        float ov = __shfl_xor(best, d, 64);
        int   oi = __shfl_xor(km,   d, 64);
        if (ov > best || (ov == best && oi < km)){ best = ov; km = oi; }
      }
      float pbv = (sq < 3) ? yb[120+sq] + gpe : -1e30f;
      int pbi = sq;
      #pragma unroll
      for (int d = 1; d <= 2; d <<= 1){
        float ov = __shfl_xor(pbv, d, 64);
        int   oi = __shfl_xor(pbi, d, 64);
        if (ov > pbv || (ov == pbv && oi < pbi)){ pbv = ov; pbi = oi; }
      }
      if (sq == 0){
        const float mx = yb[20+km], my = yb[40+km];
        const float sx = expf(yb[60+km]), sy = expf(yb[80+km]);
        const float rho = tanhf(yb[100+km]);
        const float dxs = mx + sx*e0;
        const float dys = my + sy*(rho*e0 + sqrtf(1.0f - rho*rho)*e1);
        float s0,s1,s2,s3,s4;
        if (pbi == 2){ s0=0.f; s1=0.f; s2=0.f; s3=0.f; s4=1.f; }
        else { s0=dxs; s1=dys; s2=(pbi==0)?1.f:0.f; s3=(pbi==1)?1.f:0.f; s4=0.f; }
        if (bid == 0){
          float* o = out + ((t-1)*128 + sb)*5;
          st_cg(o+0, s0); st_cg(o+1, s1); st_cg(o+2, s2); st_cg(o+3, s3); st_cg(o+4, s4);
        }
        lds_prev[sb*9+0]=s0; lds_prev[sb*9+1]=s1; lds_prev[sb*9+2]=s2;
        lds_prev[sb*9+3]=s3; lds_prev[sb*9+4]=s4;
      }
      __syncthreads();
    }
    if (t == 128) break;
    if (tid < 128){
      const int b = tid;
      const float pv0 = lds_prev[b*9+0], pv1 = lds_prev[b*9+1], pv2 = lds_prev[b*9+2],
                  pv3 = lds_prev[b*9+3], pv4 = lds_prev[b*9+4];
      const float4 c4 = ((const float4*)lds_cg4)[b];
      const float cg4f[4] = {c4.x, c4.y, c4.z, c4.w};
      float gv[4];
      #pragma unroll
      for (int gi = 0; gi < 4; ++gi)
        gv[gi] = lds_Gp[b*5 + gi] + cg4f[gi]
               + pv0*lds_hwxp[gi*5+0] + pv1*lds_hwxp[gi*5+1] + pv2*lds_hwxp[gi*5+2]
               + pv3*lds_hwxp[gi*5+3] + pv4*lds_hwxp[gi*5+4];
      const float chn = sigf(gv[1])*chst + sigf(gv[0])*tanhf(gv[2]);
      chst = chn;
      const float hhn = sigf(gv[3])*tanhf(chn);
      st_cg(&hhws[(b << 8) + bid], hhn);
    }
    gridbar(barc, ++barno);

    //---------------- P3: dX/dH/dB via Weff (regs) + main LSTM ----------------
    {
      float* lds_scr = lds_h;
      const float4* hq = (const float4*)hhws;   // quad index b*64 + l
      const int b0 = bh*64;
      float4 pf[4];
      #pragma unroll
      for (int i = 0; i < 4; ++i) pf[i] = hq[(b0 + i)*64 + l];
      #pragma unroll 4
      for (int it = 0; it < 64; ++it){
        const float4 ch = pf[it & 3];
        if (it < 60) pf[it & 3] = hq[(b0 + it + 4)*64 + l];
        const int b = b0 + it;
        float v[12];
        #pragma unroll
        for (int q = 0; q < 12; ++q) v[q] = dot4(ch, wf[q]);
        // split-reduce 12 vals over 64 lanes
        {
          const bool b5 = (l & 32), b4_ = (l & 16), b3 = (l & 8);
          #pragma unroll
          for (int q = 0; q < 6; ++q){
            float snd = b5 ? v[q] : v[q+6];
            float rcv = __shfl_xor(snd, 32, 64);
            v[q] = (b5 ? v[q+6] : v[q]) + rcv;
          }
          #pragma unroll
          for (int q = 0; q < 3; ++q){
            float snd = b4_ ? v[q] : v[q+3];
            float rcv = __shfl_xor(snd, 16, 64);
            v[q] = (b4_ ? v[q+3] : v[q]) + rcv;
          }
          float snd = b3 ? v[0] : v[1];
          float rcv = __shfl_xor(snd, 8, 64);
          float ab = (b3 ? v[1] : v[0]) + rcv;
          ab += __shfl_xor(ab, 4, 64);
          ab += __shfl_xor(ab, 2, 64);
          ab += __shfl_xor(ab, 1, 64);
          float c2 = v[2];
          c2 += __shfl_xor(c2, 8, 64);
          c2 += __shfl_xor(c2, 4, 64);
          c2 += __shfl_xor(c2, 2, 64);
          c2 += __shfl_xor(c2, 1, 64);
          const int base = (b5 ? 6 : 0) + (b4_ ? 3 : 0);
          if ((l & 15) == 0){
            lds_scr[b*50 + rq*12 + base + 0] = ab;
            lds_scr[b*50 + rq*12 + base + 2] = c2;
          } else if ((l & 15) == 8){
            lds_scr[b*50 + rq*12 + base + 1] = ab;
          }
        }
      }
      __syncthreads();
      // elementwise main LSTM (b = eb, col j = ej)
      {
        float pv[5];
        #pragma unroll
        for (int p = 0; p < 5; ++p) pv[p] = lds_prev[eb*9 + p];
        const float4 cg = ((const float4*)lds_cgx)[tid];
        const float cgxf[4] = {cg.x, cg.y, cg.z, cg.w};
        float pre[4];
        #pragma unroll
        for (int k = 0; k < 4; ++k){
          const float dXv = lds_scr[eb*50 + k*12 + ej];
          const float dHv = lds_scr[eb*50 + k*12 + 4 + ej];
          const float dBv = lds_scr[eb*50 + k*12 + 8 + ej];
          float gxv = cgxf[k];
          #pragma unroll
          for (int p = 0; p < 5; ++p) gxv += pv[p]*lds_wxp[(k*4+ej)*5 + p];
          pre[k] = dXv*gxv + dHv*lds_GH[eb*17 + k*4 + ej] + dBv + lds_b0[k*4+ej];
        }
        const float cn = sigf(pre[1])*cst + sigf(pre[0])*tanhf(pre[2]);
        cst = cn;
        const float hn = sigf(pre[3])*tanhf(cn);
        st_cg(&hws[(eb << 10) + bid*4 + ej], hn);
      }
    }
    gridbar(barc, ++barno);
  }
}

extern "C" void kernel_launch(void* const* d_in, const int* in_sizes, int n_in,
                              void* d_out, int out_size, void* d_ws, size_t ws_size,
                              hipStream_t stream)
{
  const float* z     = (const float*)d_in[0];
  const float* cls   = (const float*)d_in[1];
  const float* fcW   = (const float*)d_in[2];
  const float* fcb   = (const float*)d_in[3];
  const float* Wx    = (const float*)d_in[4];
  const float* Wh    = (const float*)d_in[5];
  const float* bias0 = (const float*)d_in[6];
  const float* hWx   = (const float*)d_in[7];
  const float* hWh   = (const float*)d_in[8];
  const float* hb    = (const float*)d_in[9];
  const float* Whz_x = (const float*)d_in[10];
  const float* Whz_h = (const float*)d_in[11];
  const float* Whz_b = (const float*)d_in[12];
  const float* Wdz_x = (const float*)d_in[13];
  const float* Wdz_h = (const float*)d_in[14];
  const float* Wdz_b = (const float*)d_in[15];
  const float* projW = (const float*)d_in[16];
  const float* projb = (const float*)d_in[17];
  const float* eps_  = (const float*)d_in[18];
  const float* umix  = (const float*)d_in[19];
  const float* upen  = (const float*)d_in[20];
  float* out = (float*)d_out;
  float* ws  = (float*)d_ws;

  void* args[] = { (void*)&z, (void*)&cls, (void*)&fcW, (void*)&fcb, (void*)&Wx, (void*)&Wh,
                   (void*)&bias0, (void*)&hWx, (void*)&hWh, (void*)&hb,
                   (void*)&Whz_x, (void*)&Whz_h, (void*)&Whz_b,
                   (void*)&Wdz_x, (void*)&Wdz_h, (void*)&Wdz_b,
                   (void*)&projW, (void*)&projb, (void*)&eps_, (void*)&umix, (void*)&upen,
                   (void*)&out, (void*)&ws };
  (void)hipLaunchCooperativeKernel((const void*)vae_kernel, dim3(NBLK), dim3(NTHR), args, 0, stream);
}

// Round 13
// 17096.452 us; speedup vs baseline: 1.1062x; 1.1062x over previous
//
#include <hip/hip_runtime.h>
#include <hip/hip_cooperative_groups.h>

namespace cg = cooperative_groups;

#define NBLK 256
#define NTHR 512

// workspace layout (float offsets)
constexpr int WS_H    = 0;            // 128*1024   h state (MALL-coherent via sc stores)
constexpr int WS_HHS  = 131072;       // 128*256    hh state
constexpr int WS_Y    = 163840;       // 128*128    y = proj output
constexpr int WS_WEFF = 180224;       // 256*12288  folded hyper weights (plain, L2-cached)
constexpr int WS_BAR  = WS_WEFF + 256*12288;   // barrier counters (uint), 128B-padded
// layout (uint idx): root @0 ; leaf[g] @ 32+g*32 (g=0..15) ; go[g] @ 544+g*32

__device__ __forceinline__ float dot4(float4 a, float4 b){
  return a.x*b.x + a.y*b.y + a.z*b.z + a.w*b.w;
}
__device__ __forceinline__ float sigf(float x){ return 1.0f/(1.0f + expf(-x)); }
__device__ __forceinline__ float gumb(float u){
  u = fminf(fmaxf(u, 1e-7f), 1.0f - 1e-7f);
  return -logf(-logf(u));
}

// coherent write-through store (reaches MALL; vmcnt-tracked)
__device__ __forceinline__ void st_cg(float* p, float v){
  asm volatile("global_store_dword %0, %1, off sc0 sc1" :: "v"(p), "v"(v) : "memory");
}

// grid barrier (16 groups x 16 blocks, broadcast release)
__device__ __forceinline__ void gridbar(unsigned* barc, unsigned n){
  asm volatile("s_waitcnt vmcnt(0)" ::: "memory");
  __syncthreads();
  if (threadIdx.x == 0){
    const unsigned g = blockIdx.x >> 4;
    unsigned old = __hip_atomic_fetch_add(barc + 32 + g*32, 1u,
                     __ATOMIC_RELAXED, __HIP_MEMORY_SCOPE_AGENT);
    if (old + 1 == n*16)
      __hip_atomic_fetch_add(barc, 1u, __ATOMIC_RELAXED, __HIP_MEMORY_SCOPE_AGENT);
    if ((blockIdx.x & 15) == 0){
      while (__hip_atomic_load(barc, __ATOMIC_RELAXED, __HIP_MEMORY_SCOPE_AGENT) < n*16)
        __builtin_amdgcn_s_sleep(1);
      __hip_atomic_store(barc + 544 + g*32, n, __ATOMIC_RELAXED, __HIP_MEMORY_SCOPE_AGENT);
    } else {
      while (__hip_atomic_load(barc + 544 + g*32, __ATOMIC_RELAXED, __HIP_MEMORY_SCOPE_AGENT) < n)
        __builtin_amdgcn_s_sleep(1);
    }
  }
  __syncthreads();
  __builtin_amdgcn_fence(__ATOMIC_ACQUIRE, "agent");
}

// Register windows (target <=128 live everywhere):
//  P1: wWh 64 (reloaded per step, dead outside P1) + A/B prefetch 40 + acc/misc ~25
//  P3: wf 48 + pf 16 + v 12 + misc (no wWh)
//  persistent scalars cgxr/cg4r live in LDS.
// P1 partition: wave (rq,bh) = gate rq rows x batch-half bh (64 batches/wave).
// Proj row r owned by block PAIR {2r, 2r+1}: batch-bit-2 selects the half ->
// per-wave proj tail is 8 dots (was 16), trimming the barrier-critical wave.
extern "C" __global__ void __launch_bounds__(NTHR, 1)
vae_kernel(const float* __restrict__ z,     const float* __restrict__ cls,
           const float* __restrict__ fcW,   const float* __restrict__ fcb,
           const float* __restrict__ Wx,    const float* __restrict__ Wh,
           const float* __restrict__ bias0, const float* __restrict__ hWx,
           const float* __restrict__ hWh,   const float* __restrict__ hb,
           const float* __restrict__ Whz_x, const float* __restrict__ Whz_h,
           const float* __restrict__ Whz_b, const float* __restrict__ Wdz_x,
           const float* __restrict__ Wdz_h, const float* __restrict__ Wdz_b,
           const float* __restrict__ projW, const float* __restrict__ projb,
           const float* __restrict__ eps_,  const float* __restrict__ umix,
           const float* __restrict__ upen,
           float* __restrict__ out, float* __restrict__ ws)
{
  cg::grid_group grid = cg::this_grid();
  const int tid = threadIdx.x;
  const int bid = blockIdx.x;
  const int l = tid & 63;          // lane
  const int w = tid >> 6;          // wave 0..7
  const int rq = w & 3;            // gate index (P1/P3)
  const int bh = w >> 2;           // batch-half (P1/P3)

  float* hws   = ws + WS_H;
  float* hhws  = ws + WS_HHS;
  float* yws   = ws + WS_Y;
  float* weffw = ws + WS_WEFF;
  unsigned* barc = (unsigned*)(ws + WS_BAR);

  // LDS (~119 KB)
  __shared__ __align__(16) float lds_h[16896];   // P2 y 128x132 / P3 scr 128x50
  __shared__ __align__(16) float lds_GH[2176];   // GH[b][17]
  __shared__ __align__(16) float lds_Gp[640];    // Gp[b][5]
  __shared__ __align__(16) float lds_prev[1152]; // prev[b][9]
  __shared__ __align__(16) float lds_hWxs[4096]; // hWx h-cols per gate
  __shared__ __align__(16) float lds_hWhs[1024]; // hWh per gate
  __shared__ __align__(16) float lds_pj[1024];   // proj row
  __shared__ __align__(16) float lds_cgx[2048];  // cgxr[tid][4]
  __shared__ __align__(16) float lds_cg4[512];   // cg4r[b][4] (b<128)
  __shared__ float lds_wxp[80];
  __shared__ float lds_hwxp[20];
  __shared__ float lds_b0[16];

  //==================== INIT ====================
  if (bid == 0 && tid < 33){
    unsigned* pc = (tid == 0) ? barc
                 : (tid < 17) ? (barc + 32 + (tid-1)*32)
                              : (barc + 544 + (tid-17)*32);
    __hip_atomic_store(pc, 0u, __ATOMIC_RELAXED, __HIP_MEMORY_SCOPE_AGENT);
  }

  // proj row r=bid>>1 on block pair {2r, 2r+1}; X=bid&1 selects batch-bit-2 half
  const bool isproj = (bid < 246);
  const int prow = bid >> 1;
  const int pX   = bid & 1;
  float pjb = 0.f;
  if (isproj) pjb = projb[prow];

  // --- LDS weight staging: hWx h-cols per gate, hWh per gate, proj row ---
  for (int i = tid; i < 4096; i += NTHR){
    int gi = i >> 10, c = i & 1023;
    lds_hWxs[i] = hWx[(size_t)(gi*256 + bid)*1167 + 143 + c];
  }
  for (int i = tid; i < 1024; i += NTHR){
    int gi = i >> 8, c = i & 255;
    lds_hWhs[i] = hWh[(((size_t)(gi*256 + bid)) << 8) + c];
  }
  if (isproj)
    for (int i = tid; i < 1024; i += NTHR)
      lds_pj[i] = projW[((size_t)prow << 10) + i];

  // --- per-thread elementwise state (b = tid>>2, j = tid&3); cgxr/cg4r -> LDS ---
  const int eb = tid >> 2, ej = tid & 3;
  #pragma unroll
  for (int k = 0; k < 4; ++k){
    const float* wr = Wx + (size_t)(k*1024 + bid*4 + ej)*143;
    float a = 0.f;
    for (int n = 0; n < 10; ++n) a += cls[eb*10+n]*wr[5+n];
    const float* zr = z + (eb << 7);
    #pragma unroll 8
    for (int i = 0; i < 128; ++i) a += zr[i]*wr[15+i];
    lds_cgx[tid*4+k] = a;
  }
  float cst;
  {
    int col = 1024 + bid*4 + ej;
    float a = fcb[col];
    const float* wr = fcW + (col << 7);
    const float* zr = z + (eb << 7);
    #pragma unroll 8
    for (int i = 0; i < 128; ++i) a += zr[i]*wr[i];
    cst = tanhf(a);
  }
  {
    int col = bid*4 + ej;
    float a = fcb[col];
    const float* wr = fcW + (col << 7);
    const float* zr = z + (eb << 7);
    #pragma unroll 8
    for (int i = 0; i < 128; ++i) a += zr[i]*wr[i];
    st_cg(&hws[(eb << 10) + col], tanhf(a));
  }
  float chst = 0.f;
  if (tid < 128){
    int b = tid;
    const float* zr = z + (b << 7);
    #pragma unroll
    for (int gi = 0; gi < 4; ++gi){
      int row = gi*256 + bid;
      const float* wr = hWx + (size_t)row*1167;
      float a = hb[row];
      for (int n = 0; n < 10; ++n) a += cls[b*10+n]*wr[5+n];
      #pragma unroll 8
      for (int i = 0; i < 128; ++i) a += zr[i]*wr[15+i];
      lds_cg4[b*4+gi] = a;
    }
    {
      int col = 2304 + bid;
      float a = fcb[col];
      const float* wr = fcW + (col << 7);
      #pragma unroll 8
      for (int i = 0; i < 128; ++i) a += zr[i]*wr[i];
      chst = tanhf(a);
    }
    {
      int col = 2048 + bid;
      float a = fcb[col];
      const float* wr = fcW + (col << 7);
      #pragma unroll 8
      for (int i = 0; i < 128; ++i) a += zr[i]*wr[i];
      st_cg(&hhws[(b << 8) + bid], tanhf(a));
    }
    lds_prev[tid*9+0] = 0.f; lds_prev[tid*9+1] = 0.f; lds_prev[tid*9+2] = 1.f;
    lds_prev[tid*9+3] = 0.f; lds_prev[tid*9+4] = 0.f;
  }
  if (tid < 80){
    int r16 = tid/5, p = tid - r16*5;
    lds_wxp[tid] = Wx[(size_t)((r16>>2)*1024 + bid*4 + (r16&3))*143 + p];
  }
  if (tid < 20){
    int gi = tid/5, p = tid - gi*5;
    lds_hwxp[tid] = hWx[(size_t)(gi*256 + bid)*1167 + p];
  }
  if (tid < 16) lds_b0[tid] = bias0[(tid>>2)*1024 + bid*4 + (tid&3)];

  // --- Weff fold: Weff_m[r=k*4+j][c] = sum_z Wdz_m[k*1024+bid*4+j][z] * Whz_m[k*64+z][c] ---
  {
    const float* Wdzp[3] = {Wdz_x, Wdz_h, Wdz_b};
    const float* Whzp[3] = {Whz_x, Whz_h, Whz_b};
    for (int n = 0; n < 24; ++n){
      int gidx = tid + 512*n;
      int m = gidx >> 12, rem = gidx & 4095;
      int r = rem >> 8, c = rem & 255;
      int k = r >> 2, j = r & 3;
      const float* wd = Wdzp[m] + (size_t)(k*1024 + bid*4 + j)*64;
      const float* wzb = Whzp[m] + c;
      float a = 0.f;
      #pragma unroll 8
      for (int zz = 0; zz < 64; ++zz) a += wd[zz]*wzb[(k*64+zz) << 8];
      weffw[(size_t)bid*12288 + gidx] = a;
    }
  }
  grid.sync();   // publishes init state + zeroed counters

  unsigned barno = 0;

  const float4* wx4  = (const float4*)lds_hWxs + (rq << 8);
  const float4* whh4 = (const float4*)lds_hWhs + (rq << 6);
  const float4* pj4  = (const float4*)lds_pj;

  //==================== time loop ====================
  for (int t = 0; t <= 128; ++t){
    //---------------- P1: wave (rq,bh) -> gate rq rows, batches bh*64..+63 ----------------
    {
      // gate-rq Wh rows reloaded per step (keeps P3's register window clean)
      float4 wWh[4][4];
      #pragma unroll
      for (int j = 0; j < 4; ++j){
        const int row = rq*1024 + bid*4 + j;
        #pragma unroll
        for (int m = 0; m < 4; ++m)
          wWh[j][m] = *((const float4*)(Wh + ((size_t)row << 10) + m*256) + l);
      }

      auto p1c = [&](float4 a0, float4 a1, float4 a2, float4 a3, float4 hv, int b){
        float acc[4];
        #pragma unroll
        for (int j = 0; j < 4; ++j)
          acc[j] = dot4(a0,wWh[j][0]) + dot4(a1,wWh[j][1])
                 + dot4(a2,wWh[j][2]) + dot4(a3,wWh[j][3]);
        float gac = dot4(a0, wx4[l]) + dot4(a1, wx4[64+l]) + dot4(a2, wx4[128+l])
                  + dot4(a3, wx4[192+l]) + dot4(hv, whh4[l]);
        const bool b5 = (l & 32), b4_ = (l & 16), b3 = (l & 8);
        // stage 32: acc pairs split; gac butterflies along
        #pragma unroll
        for (int q = 0; q < 2; ++q){
          float snd = b5 ? acc[q] : acc[q+2];
          float rcv = __shfl_xor(snd, 32, 64);
          acc[q] = (b5 ? acc[q+2] : acc[q]) + rcv;
        }
        gac += __shfl_xor(gac, 32, 64);
        // stage 16
        {
          float snd = b4_ ? acc[0] : acc[1];
          float rcv = __shfl_xor(snd, 16, 64);
          acc[0] = (b4_ ? acc[1] : acc[0]) + rcv;
        }
        gac += __shfl_xor(gac, 16, 64);
        // stage 8: split acc vs gac, shared butterfly
        {
          float snd = b3 ? acc[0] : gac;
          float rcv = __shfl_xor(snd, 8, 64);
          float s = (b3 ? gac : acc[0]) + rcv;
          s += __shfl_xor(s, 4, 64);
          s += __shfl_xor(s, 2, 64);
          s += __shfl_xor(s, 1, 64);
          if ((l & 15) == 0)
            lds_GH[b*17 + rq*4 + (b5 ? 2 : 0) + (b4_ ? 1 : 0)] = s;
          else if (l == 8)
            lds_Gp[b*5 + rq] = s;
        }
        // proj row: gate-wave balance via (b&3)==rq, pair-half via batch bit 2
        if (isproj && ((b & 3) == rq) && (((b >> 2) & 1) == pX)){
          float ya = dot4(a0,pj4[l]) + dot4(a1,pj4[64+l]) + dot4(a2,pj4[128+l])
                   + dot4(a3,pj4[192+l]);
          ya += __shfl_xor(ya, 32, 64);
          ya += __shfl_xor(ya, 16, 64);
          ya += __shfl_xor(ya, 8, 64);
          ya += __shfl_xor(ya, 4, 64);
          ya += __shfl_xor(ya, 2, 64);
          ya += __shfl_xor(ya, 1, 64);
          if (l == 0) st_cg(&yws[(b << 7) + prow], ya + pjb);
        }
      };

      const float4* hb4  = (const float4*)hws;    // 256 float4 per batch
      const float4* hhb4 = (const float4*)hhws;   // 64 float4 per batch
      const int bq = bh*64;
      float4 A0,A1,A2,A3,AH, B0,B1,B2,B3,BH;
      {
        const float4* hp = hb4 + ((size_t)bq << 8);
        A0 = hp[l]; A1 = hp[64+l]; A2 = hp[128+l]; A3 = hp[192+l];
        AH = hhb4[(bq << 6) + l];
        const float4* hp2 = hb4 + ((size_t)(bq+1) << 8);
        B0 = hp2[l]; B1 = hp2[64+l]; B2 = hp2[128+l]; B3 = hp2[192+l];
        BH = hhb4[((bq+1) << 6) + l];
      }
      for (int it = 0; it < 64; it += 2){
        p1c(A0,A1,A2,A3,AH, bq+it);
        if (it < 62){
          const float4* hp = hb4 + ((size_t)(bq+it+2) << 8);
          A0 = hp[l]; A1 = hp[64+l]; A2 = hp[128+l]; A3 = hp[192+l];
          AH = hhb4[((bq+it+2) << 6) + l];
        }
        p1c(B0,B1,B2,B3,BH, bq+it+1);
        if (it < 62){
          const float4* hp = hb4 + ((size_t)(bq+it+3) << 8);
          B0 = hp[l]; B1 = hp[64+l]; B2 = hp[128+l]; B3 = hp[192+l];
          BH = hhb4[((bq+it+3) << 6) + l];
        }
      }
    }
    gridbar(barc, ++barno);

    // prefetch P3 folded weights (own-block, read-only) — latency hides under P2
    float4 wf[12];
    #pragma unroll
    for (int m = 0; m < 3; ++m)
      #pragma unroll
      for (int j = 0; j < 4; ++j)
        wf[m*4+j] = *((const float4*)(weffw + (size_t)bid*12288 + m*4096 + ((rq*4+j) << 8)) + l);

    //---------------- P2: sampling (t-1, redundant per block), 4 lanes/batch ----------------
    if (t >= 1){
      // y copy global->LDS padded stride 132 (all 512 threads)
      {
        const float4* ysrc = (const float4*)yws;
        float4 q4[8];
        #pragma unroll
        for (int k = 0; k < 8; ++k) q4[k] = ysrc[(tid>>2)*32 + (tid&3)*8 + k];
        float4* dst = (float4*)(lds_h + (tid>>2)*132 + (tid&3)*32);
        #pragma unroll
        for (int k = 0; k < 8; ++k) dst[k] = q4[k];
      }
      const int sb = tid >> 2, sq = tid & 3;   // batch, quarter
      float gm[5];
      #pragma unroll
      for (int i = 0; i < 5; ++i) gm[i] = gumb(umix[((t-1)*128 + sb)*20 + sq*5 + i]);
      const float gpe = (sq < 3) ? gumb(upen[((t-1)*128 + sb)*3 + sq]) : -1e30f;
      const float e0 = eps_[((t-1)*128 + sb)*2 + 0];
      const float e1 = eps_[((t-1)*128 + sb)*2 + 1];
      __syncthreads();
      const float* yb = lds_h + sb*132;
      float best = -1e30f; int km = 0;
      #pragma unroll
      for (int i = 0; i < 5; ++i){
        float v = yb[sq*5+i] + gm[i];
        if (v > best){ best = v; km = sq*5+i; }
      }
      #pragma unroll
      for (int d = 1; d <= 2; d <<= 1){
        float ov = __shfl_xor(best, d, 64);
        int   oi = __shfl_xor(km,   d, 64);
        if (ov > best || (ov == best && oi < km)){ best = ov; km = oi; }
      }
      float pbv = (sq < 3) ? yb[120+sq] + gpe : -1e30f;
      int pbi = sq;
      #pragma unroll
      for (int d = 1; d <= 2; d <<= 1){
        float ov = __shfl_xor(pbv, d, 64);
        int   oi = __shfl_xor(pbi, d, 64);
        if (ov > pbv || (ov == pbv && oi < pbi)){ pbv = ov; pbi = oi; }
      }
      if (sq == 0){
        const float mx = yb[20+km], my = yb[40+km];
        const float sx = expf(yb[60+km]), sy = expf(yb[80+km]);
        const float rho = tanhf(yb[100+km]);
        const float dxs = mx + sx*e0;
        const float dys = my + sy*(rho*e0 + sqrtf(1.0f - rho*rho)*e1);
        float s0,s1,s2,s3,s4;
        if (pbi == 2){ s0=0.f; s1=0.f; s2=0.f; s3=0.f; s4=1.f; }
        else { s0=dxs; s1=dys; s2=(pbi==0)?1.f:0.f; s3=(pbi==1)?1.f:0.f; s4=0.f; }
        if (bid == 0){
          float* o = out + ((t-1)*128 + sb)*5;
          st_cg(o+0, s0); st_cg(o+1, s1); st_cg(o+2, s2); st_cg(o+3, s3); st_cg(o+4, s4);
        }
        lds_prev[sb*9+0]=s0; lds_prev[sb*9+1]=s1; lds_prev[sb*9+2]=s2;
        lds_prev[sb*9+3]=s3; lds_prev[sb*9+4]=s4;
      }
      __syncthreads();
    }
    if (t == 128) break;
    if (tid < 128){
      const int b = tid;
      const float pv0 = lds_prev[b*9+0], pv1 = lds_prev[b*9+1], pv2 = lds_prev[b*9+2],
                  pv3 = lds_prev[b*9+3], pv4 = lds_prev[b*9+4];
      const float4 c4 = ((const float4*)lds_cg4)[b];
      const float cg4f[4] = {c4.x, c4.y, c4.z, c4.w};
      float gv[4];
      #pragma unroll
      for (int gi = 0; gi < 4; ++gi)
        gv[gi] = lds_Gp[b*5 + gi] + cg4f[gi]
               + pv0*lds_hwxp[gi*5+0] + pv1*lds_hwxp[gi*5+1] + pv2*lds_hwxp[gi*5+2]
               + pv3*lds_hwxp[gi*5+3] + pv4*lds_hwxp[gi*5+4];
      const float chn = sigf(gv[1])*chst + sigf(gv[0])*tanhf(gv[2]);
      chst = chn;
      const float hhn = sigf(gv[3])*tanhf(chn);
      st_cg(&hhws[(b << 8) + bid], hhn);
    }
    gridbar(barc, ++barno);

    //---------------- P3: dX/dH/dB via Weff (regs) + main LSTM ----------------
    {
      float* lds_scr = lds_h;
      const float4* hq = (const float4*)hhws;   // quad index b*64 + l
      const int b0 = bh*64;
      float4 pf[4];
      #pragma unroll
      for (int i = 0; i < 4; ++i) pf[i] = hq[(b0 + i)*64 + l];
      #pragma unroll 4
      for (int it = 0; it < 64; ++it){
        const float4 ch = pf[it & 3];
        if (it < 60) pf[it & 3] = hq[(b0 + it + 4)*64 + l];
        const int b = b0 + it;
        float v[12];
        #pragma unroll
        for (int q = 0; q < 12; ++q) v[q] = dot4(ch, wf[q]);
        // split-reduce 12 vals over 64 lanes
        {
          const bool b5 = (l & 32), b4_ = (l & 16), b3 = (l & 8);
          #pragma unroll
          for (int q = 0; q < 6; ++q){
            float snd = b5 ? v[q] : v[q+6];
            float rcv = __shfl_xor(snd, 32, 64);
            v[q] = (b5 ? v[q+6] : v[q]) + rcv;
          }
          #pragma unroll
          for (int q = 0; q < 3; ++q){
            float snd = b4_ ? v[q] : v[q+3];
            float rcv = __shfl_xor(snd, 16, 64);
            v[q] = (b4_ ? v[q+3] : v[q]) + rcv;
          }
          float snd = b3 ? v[0] : v[1];
          float rcv = __shfl_xor(snd, 8, 64);
          float ab = (b3 ? v[1] : v[0]) + rcv;
          ab += __shfl_xor(ab, 4, 64);
          ab += __shfl_xor(ab, 2, 64);
          ab += __shfl_xor(ab, 1, 64);
          float c2 = v[2];
          c2 += __shfl_xor(c2, 8, 64);
          c2 += __shfl_xor(c2, 4, 64);
          c2 += __shfl_xor(c2, 2, 64);
          c2 += __shfl_xor(c2, 1, 64);
          const int base = (b5 ? 6 : 0) + (b4_ ? 3 : 0);
          if ((l & 15) == 0){
            lds_scr[b*50 + rq*12 + base + 0] = ab;
            lds_scr[b*50 + rq*12 + base + 2] = c2;
          } else if ((l & 15) == 8){
            lds_scr[b*50 + rq*12 + base + 1] = ab;
          }
        }
      }
      __syncthreads();
      // elementwise main LSTM (b = eb, col j = ej)
      {
        float pv[5];
        #pragma unroll
        for (int p = 0; p < 5; ++p) pv[p] = lds_prev[eb*9 + p];
        const float4 cg = ((const float4*)lds_cgx)[tid];
        const float cgxf[4] = {cg.x, cg.y, cg.z, cg.w};
        float pre[4];
        #pragma unroll
        for (int k = 0; k < 4; ++k){
          const float dXv = lds_scr[eb*50 + k*12 + ej];
          const float dHv = lds_scr[eb*50 + k*12 + 4 + ej];
          const float dBv = lds_scr[eb*50 + k*12 + 8 + ej];
          float gxv = cgxf[k];
          #pragma unroll
          for (int p = 0; p < 5; ++p) gxv += pv[p]*lds_wxp[(k*4+ej)*5 + p];
          pre[k] = dXv*gxv + dHv*lds_GH[eb*17 + k*4 + ej] + dBv + lds_b0[k*4+ej];
        }
        const float cn = sigf(pre[1])*cst + sigf(pre[0])*tanhf(pre[2]);
        cst = cn;
        const float hn = sigf(pre[3])*tanhf(cn);
        st_cg(&hws[(eb << 10) + bid*4 + ej], hn);
      }
    }
    gridbar(barc, ++barno);
  }
}

extern "C" void kernel_launch(void* const* d_in, const int* in_sizes, int n_in,
                              void* d_out, int out_size, void* d_ws, size_t ws_size,
                              hipStream_t stream)
{
  const float* z     = (const float*)d_in[0];
  const float* cls   = (const float*)d_in[1];
  const float* fcW   = (const float*)d_in[2];
  const float* fcb   = (const float*)d_in[3];
  const float* Wx    = (const float*)d_in[4];
  const float* Wh    = (const float*)d_in[5];
  const float* bias0 = (const float*)d_in[6];
  const float* hWx   = (const float*)d_in[7];
  const float* hWh   = (const float*)d_in[8];
  const float* hb    = (const float*)d_in[9];
  const float* Whz_x = (const float*)d_in[10];
  const float* Whz_h = (const float*)d_in[11];
  const float* Whz_b = (const float*)d_in[12];
  const float* Wdz_x = (const float*)d_in[13];
  const float* Wdz_h = (const float*)d_in[14];
  const float* Wdz_b = (const float*)d_in[15];
  const float* projW = (const float*)d_in[16];
  const float* projb = (const float*)d_in[17];
  const float* eps_  = (const float*)d_in[18];
  const float* umix  = (const float*)d_in[19];
  const float* upen  = (const float*)d_in[20];
  float* out = (float*)d_out;
  float* ws  = (float*)d_ws;

  void* args[] = { (void*)&z, (void*)&cls, (void*)&fcW, (void*)&fcb, (void*)&Wx, (void*)&Wh,
                   (void*)&bias0, (void*)&hWx, (void*)&hWh, (void*)&hb,
                   (void*)&Whz_x, (void*)&Whz_h, (void*)&Whz_b,
                   (void*)&Wdz_x, (void*)&Wdz_h, (void*)&Wdz_b,
                   (void*)&projW, (void*)&projb, (void*)&eps_, (void*)&umix, (void*)&upen,
                   (void*)&out, (void*)&ws };
  (void)hipLaunchCooperativeKernel((const void*)vae_kernel, dim3(NBLK), dim3(NTHR), args, 0, stream);
}